// Round 8
// baseline (654.388 us; speedup 1.0000x reference)
//
#include <hip/hip_runtime.h>
#include <hip/hip_bf16.h>
#include <stdint.h>

// SememeRGCN on MI355X, v9: 32-node blocks -> 4 blocks/CU (16 waves).
// v3-v8 lesson: five gather schedules all ~120us/layer at 8 waves/CU (2
// blocks, 48KB LDS); v2's LDS-free standalone aggregator moved more bytes in
// <60us at ~16+ waves/CU -> random-gather rate scales with RESIDENT WAVES,
// not per-wave issue depth. v9 shrinks the M-tile to 32 nodes: LDS = 8KB A +
// 32KB B = 40KB -> 4 blocks/CU; while one block is in MFMA/barrier the other
// three gather. Per wave: 8 nodes, 1 pass, 12-load burst (48 VGPR), fits the
// 128-VGPR cap at 4 waves/SIMD. Everything else as v8 (pre-swizzled WT via
// global_load_lds, lane-parallel accumulate, csr/offs prefetch pipeline).

#define N_NODES 50000
#define N_EDGES 800000
#define R_REL 8
#define NSEG (N_NODES * R_REL)   // 400000 (rel, node) segments
#define MB 32                    // nodes per block

typedef __bf16 bf16_8 __attribute__((ext_vector_type(8)));
typedef float floatx4 __attribute__((ext_vector_type(4)));

static __device__ __forceinline__ float bf2f(unsigned short v) {
    unsigned u = ((unsigned)v) << 16;
    return __builtin_bit_cast(float, u);
}
static __device__ __forceinline__ unsigned short f2bf(float f) {
    unsigned u = __builtin_bit_cast(unsigned, f);
    u += 0x7FFFu + ((u >> 16) & 1u);   // round-to-nearest-even
    return (unsigned short)(u >> 16);
}
static __device__ __forceinline__ float bitf(unsigned u) {
    return __builtin_bit_cast(float, u);
}
// swizzled LDS byte offset: row-major 256B rows, XOR row bits into 16B slot
static __device__ __forceinline__ int sw(int row, int b) {
    return (row << 8) + (b ^ ((row & 7) << 4));
}
// async global->LDS, 16B per lane; lds dest wave-uniform base + lane*16
static __device__ __forceinline__ void gl_lds16(const unsigned short* g, char* l) {
    __builtin_amdgcn_global_load_lds(
        (const __attribute__((address_space(1))) unsigned int*)g,
        (__attribute__((address_space(3))) unsigned int*)l, 16, 0, 0);
}

// ---------------- dtype detection ----------------
__global__ void k_detect(const unsigned* __restrict__ g1, unsigned* __restrict__ flag) {
    if (threadIdx.x == 0 && blockIdx.x == 0)
        flag[0] = (g1[0] == 0x3F803F80u) ? 1u : 0u;
}

// ---------------- preprocessing ----------------

__global__ void k_zero(unsigned* __restrict__ p, int n_words) {
    int i = blockIdx.x * blockDim.x + threadIdx.x;
    int stride = gridDim.x * blockDim.x;
    for (; i < n_words; i += stride) p[i] = 0u;
}

// one atomic per edge; returned value IS the edge's rank within (rel,dst)
__global__ void k_count(const int* __restrict__ ei, const int* __restrict__ et,
                        unsigned* __restrict__ cnt, unsigned* __restrict__ rank) {
    int e = blockIdx.x * 256 + threadIdx.x;
    if (e >= N_EDGES) return;
    int dst = ei[N_EDGES + e];
    int t = et[e];
    rank[e] = atomicAdd(&cnt[t * N_NODES + dst], 1u);
}

// ---- 3-phase exclusive scan of cnt[400000] -> offs[400001] ----
#define SCAN_B 1024
#define SCAN_NB ((NSEG + SCAN_B - 1) / SCAN_B)   // 391

__global__ void k_scan1(const unsigned* __restrict__ deg, unsigned* __restrict__ escan,
                        unsigned* __restrict__ bsum) {
    __shared__ unsigned wsum[16];
    int tid = threadIdx.x;
    int lane = tid & 63, wid = tid >> 6;
    int i = blockIdx.x * SCAN_B + tid;
    unsigned v = (i < NSEG) ? deg[i] : 0u;
    unsigned incl = v;
#pragma unroll
    for (int d = 1; d < 64; d <<= 1) {
        unsigned t = __shfl_up(incl, d, 64);
        if (lane >= d) incl += t;
    }
    if (lane == 63) wsum[wid] = incl;
    __syncthreads();
    if (wid == 0 && lane < 16) {
        unsigned w = wsum[lane];
#pragma unroll
        for (int d = 1; d < 16; d <<= 1) {
            unsigned t = __shfl_up(w, d, 64);
            if (lane >= d) w += t;
        }
        wsum[lane] = w;
    }
    __syncthreads();
    unsigned woff = (wid == 0) ? 0u : wsum[wid - 1];
    if (i < NSEG) escan[i] = woff + incl - v;
    if (tid == 0) bsum[blockIdx.x] = wsum[15];
}

__global__ void k_scan2(const unsigned* __restrict__ bsum, unsigned* __restrict__ boff,
                        unsigned* __restrict__ offs) {
    __shared__ unsigned ws[8];
    int tid = threadIdx.x;
    int lane = tid & 63, w = tid >> 6;
    unsigned b = (tid < SCAN_NB) ? bsum[tid] : 0u;
    unsigned incl = b;
#pragma unroll
    for (int d = 1; d < 64; d <<= 1) {
        unsigned t = __shfl_up(incl, d, 64);
        if (lane >= d) incl += t;
    }
    if (lane == 63) ws[w] = incl;
    __syncthreads();
    unsigned wpre = 0;
    for (int i = 0; i < w; ++i) wpre += ws[i];
    if (tid < SCAN_NB) boff[tid] = wpre + incl - b;
    if (tid == 511) offs[NSEG] = wpre + incl;   // grand total = N_EDGES
}

__global__ void k_scan3(const unsigned* __restrict__ escan, const unsigned* __restrict__ boff,
                        unsigned* __restrict__ offs) {
    int i = blockIdx.x * SCAN_B + threadIdx.x;
    if (i < NSEG) offs[i] = escan[i] + boff[blockIdx.x];
}

// atomic-free fill: csr entry = src (dst implicit in segment), (rel,dst) sorted
__global__ void k_fill(const int* __restrict__ ei, const int* __restrict__ et,
                       const unsigned* __restrict__ offs, const unsigned* __restrict__ rank,
                       unsigned* __restrict__ csr) {
    int e = blockIdx.x * 256 + threadIdx.x;
    if (e >= N_EDGES) return;
    int src = ei[e];
    int dst = ei[N_EDGES + e];
    int t = et[e];
    csr[offs[(size_t)t * N_NODES + dst] + rank[e]] = (unsigned)src;
}

// transpose 27 [128x128] matrices to K-major bf16 with PRE-SWIZZLED rows:
// within each 256B output row o, 16B slot s holds original slot s^(o&7).
__global__ void k_transw(const unsigned* __restrict__ flag,
                         const void* __restrict__ W1, const void* __restrict__ r1,
                         const void* __restrict__ W2, const void* __restrict__ r2,
                         const void* __restrict__ W3, const void* __restrict__ r3,
                         unsigned short* __restrict__ WT) {
    int idx = blockIdx.x * 256 + threadIdx.x;
    if (idx >= 27 * 128 * 128) return;
    int is_bf = (int)flag[0];
    int m = idx >> 14;
    int r = idx & 16383;
    int o = r >> 7, d = r & 127;
    int l = m / 9, j = m % 9;
    const void* W = (l == 0) ? W1 : (l == 1) ? W2 : W3;
    const void* rt = (l == 0) ? r1 : (l == 1) ? r2 : r3;
    size_t eoff = (size_t)d * 128 + o;
    unsigned short v;
    if (j == 0) {
        v = is_bf ? ((const unsigned short*)rt)[eoff]
                  : f2bf(((const float*)rt)[eoff]);
    } else {
        size_t base = (size_t)(j - 1) * 16384;
        v = is_bf ? ((const unsigned short*)W)[base + eoff]
                  : f2bf(((const float*)W)[base + eoff]);
    }
    int selem = o * 128 + (((d >> 3) ^ (o & 7)) << 3) + (d & 7);
    WT[m * 16384 + selem] = v;
}

// gather emb[node_ids] -> x (bf16), 4 elems per thread
__global__ void k_gather(const unsigned* __restrict__ flag,
                         const int* __restrict__ ids, const void* __restrict__ emb,
                         unsigned short* __restrict__ x) {
    int c = blockIdx.x * 256 + threadIdx.x;
    if (c >= N_NODES * 32) return;
    int is_bf = (int)flag[0];
    int row = c >> 5, k = (c & 31) << 2;
    size_t s = (size_t)ids[row] * 128 + k;
    if (is_bf) {
        *(uint2*)&x[(size_t)row * 128 + k] = *(const uint2*)((const unsigned short*)emb + s);
    } else {
        const float4 f = *(const float4*)((const float*)emb + s);
        unsigned p0 = (unsigned)f2bf(f.x) | ((unsigned)f2bf(f.y) << 16);
        unsigned p1 = (unsigned)f2bf(f.z) | ((unsigned)f2bf(f.w) << 16);
        uint2 u; u.x = p0; u.y = p1;
        *(uint2*)&x[(size_t)row * 128 + k] = u;
    }
}

// convert 7 param vectors (b1,g1,be1,b2,g2,be2,b3) to fp32 canonical copies
__global__ void k_cvtvec(const unsigned* __restrict__ flag,
                         const void* p0, const void* p1, const void* p2,
                         const void* p3, const void* p4, const void* p5,
                         const void* p6, float* __restrict__ vecs) {
    int v = blockIdx.x, i = threadIdx.x;
    const void* p = (v == 0) ? p0 : (v == 1) ? p1 : (v == 2) ? p2 :
                    (v == 3) ? p3 : (v == 4) ? p4 : (v == 5) ? p5 : p6;
    float f = flag[0] ? bf2f(((const unsigned short*)p)[i]) : ((const float*)p)[i];
    vecs[v * 128 + i] = f;
}

// accumulate 8 channels (4 dwords = 8 bf16) into acc[base..base+7]
#define ACC8(v, base)                                                          \
    {                                                                          \
        acc[(base) + 0] += bitf((v).x << 16);                                  \
        acc[(base) + 1] += bitf((v).x & 0xFFFF0000u);                          \
        acc[(base) + 2] += bitf((v).y << 16);                                  \
        acc[(base) + 3] += bitf((v).y & 0xFFFF0000u);                          \
        acc[(base) + 4] += bitf((v).z << 16);                                  \
        acc[(base) + 5] += bitf((v).z & 0xFFFF0000u);                          \
        acc[(base) + 6] += bitf((v).w << 16);                                  \
        acc[(base) + 7] += bitf((v).w & 0xFFFF0000u);                          \
    }

// ---------------- fused RGCN layer ----------------
// block = 32 nodes, 256 threads (4 waves as 2x2: 16 rows x 64 cols each).
// out[n] = [x_n | mean_0(n) | ... | mean_7(n)] @ [root; W0..7] + bias
//          (then optional LN+ReLU), K = 9*128. 40KB LDS -> 4 blocks/CU.

__global__ __launch_bounds__(256, 4) void k_fused(
    const unsigned short* __restrict__ X,     // [N,128] bf16 (layer input)
    const unsigned* __restrict__ offs,        // [NSEG+1], seg = rel*N + dst
    const unsigned* __restrict__ csr,         // [E] src ids
    const unsigned short* __restrict__ WTL,   // 9*[128][128] bf16, pre-swizzled
    const float* __restrict__ bias,
    const float* __restrict__ g,
    const float* __restrict__ be,
    void* __restrict__ outp,
    int do_ln,
    const unsigned* __restrict__ flag)
{
    __shared__ __align__(16) unsigned char lds[40960];
    char* Ab  = (char*)lds;            // 8KB A tile (32 rows x 128 k)
    char* Bsm = (char*)lds + 8192;     // 32KB B tile (128 out x 128 k)

    int tid = threadIdx.x;
    int m0 = blockIdx.x * MB;
    int lane = tid & 63, wv = tid >> 6;
    int rr = lane & 15, qq = lane >> 4;
    int wr = wv >> 1, wc = wv & 1;
    int gbw = m0 + wv * 8;             // this wave's first node (8 nodes/wave)
    int slot = lane >> 3;              // node slot (0..7)
    int cq = lane & 7;                 // 16B-pair index within row (0..7)

    // --- offs bounds: 9 lanes cover this wave's 8 nodes for rel 0 / rel 1 ---
    unsigned offA = 0, offB = 0;
    if (lane < 9) {
        int idx = gbw + lane; if (idx > N_NODES) idx = N_NODES;
        offA = offs[(size_t)0 * N_NODES + idx];
        offB = offs[(size_t)1 * N_NODES + idx];
    }

    floatx4 gac[4];
#pragma unroll
    for (int j = 0; j < 4; j++) gac[j] = (floatx4){0.f, 0.f, 0.f, 0.f};

    // prologue: issue B0 loads (async), stage x rows -> Ab (phase 0 = root)
#pragma unroll
    for (int i = 0; i < 8; ++i) {
        int cbase = i * 256 + wv * 64;           // wave-uniform chunk base
        gl_lds16(WTL + (size_t)(cbase + lane) * 8, Bsm + (size_t)cbase * 16);
    }
#pragma unroll
    for (int i = 0; i < 2; ++i) {
        int c = tid + i * 256;                   // 512 chunks of 16B
        int row = c >> 4, kg = c & 15;
        int grow = m0 + row; if (grow > N_NODES - 1) grow = N_NODES - 1;
        uint4 v = *(const uint4*)&X[(size_t)grow * 128 + kg * 8];
        *(uint4*)(Ab + sw(row, kg * 16)) = v;
    }

    // csr prefetch for rel 0 (6 entries per node-slot)
    unsigned cpA[6], cpB[6];
    {
        unsigned lo = __shfl(offA, slot, 64);
        unsigned hi = __shfl(offA, slot + 1, 64);
        unsigned cn = hi - lo;
#pragma unroll
        for (int k = 0; k < 6; ++k)
            if ((unsigned)k < cn) cpA[k] = csr[lo + k];
    }
    __syncthreads();                             // Ab + B0 landed

    for (int p = 0; p < 9; ++p) {
        // ---- MFMA phase p ----
#pragma unroll
        for (int kk = 0; kk < 4; ++kk) {
            int ko = kk * 64 + qq * 16;          // 16B chunk within 256B row
            bf16_8 a, b[4];
            a = *(const bf16_8*)(Ab + sw(wr * 16 + rr, ko));
#pragma unroll
            for (int j = 0; j < 4; ++j)
                b[j] = *(const bf16_8*)(Bsm + sw(wc * 64 + j * 16 + rr, ko));
#pragma unroll
            for (int j = 0; j < 4; ++j)
                gac[j] = __builtin_amdgcn_mfma_f32_16x16x32_bf16(a, b[j], gac[j], 0, 0, 0);
        }
        if (p == 8) break;
        __syncthreads();                         // all Ab/Bsm reads done

        // ---- stage B(p+1) async ----
        const unsigned short* WTn = WTL + (size_t)(p + 1) * 16384;
#pragma unroll
        for (int i = 0; i < 8; ++i) {
            int cbase = i * 256 + wv * 64;
            gl_lds16(WTn + (size_t)(cbase + lane) * 8, Bsm + (size_t)cbase * 16);
        }

        // ---- load burst: this wave's 8 nodes' edge rows (12 uint4 dests) ---
        unsigned lo0 = __shfl(offA, slot, 64);
        unsigned hi0 = __shfl(offA, slot + 1, 64);
        unsigned cnt0 = hi0 - lo0;
        uint4 ra[6], rb[6];
#pragma unroll
        for (int k = 0; k < 6; ++k) {
            if ((unsigned)k < cnt0) {
                const uint4* q = (const uint4*)(X + (size_t)cpA[k] * 128 + cq * 16);
                ra[k] = q[0]; rb[k] = q[1];
            }
        }

        // ---- prefetch csr entries for rel p+1 (overlaps row-load latency) --
        if (p + 1 < R_REL) {
            unsigned lo = __shfl(offB, slot, 64);
            unsigned hi = __shfl(offB, slot + 1, 64);
            unsigned cn = hi - lo;
#pragma unroll
            for (int k = 0; k < 6; ++k)
                if ((unsigned)k < cn) cpB[k] = csr[lo + k];
        }
        // ---- offs prefetch for rel p+2 ----
        unsigned offT = 0;
        if (p + 2 < R_REL && lane < 9) {
            int idx = gbw + lane; if (idx > N_NODES) idx = N_NODES;
            offT = offs[(size_t)(p + 2) * N_NODES + idx];
        }

        // ---- accumulate ----
        {
            float acc[16];
#pragma unroll
            for (int c = 0; c < 16; ++c) acc[c] = 0.f;
#pragma unroll
            for (int k = 0; k < 6; ++k)
                if ((unsigned)k < cnt0) { ACC8(ra[k], 0); ACC8(rb[k], 8); }
            unsigned i = 6;                      // rare tail (P(cnt>6)~0.5%)
            while (__any(i < cnt0)) {
                if (i < cnt0) {
                    unsigned e = csr[lo0 + i];
                    const uint4* q = (const uint4*)(X + (size_t)e * 128 + cq * 16);
                    uint4 ta = q[0], tb = q[1];
                    ACC8(ta, 0); ACC8(tb, 8);
                }
                ++i;
            }
            float inv = cnt0 ? 1.0f / (float)cnt0 : 0.0f;
            int nrow = wv * 8 + slot;
#pragma unroll
            for (int d = 0; d < 8; ++d) {
                unsigned w = (unsigned)f2bf(acc[2 * d] * inv) |
                             ((unsigned)f2bf(acc[2 * d + 1] * inv) << 16);
                *(unsigned*)(Ab + sw(nrow, cq * 32 + d * 4)) = w;
            }
        }

        // rotate prefetch registers
        offA = offB; offB = offT;
#pragma unroll
        for (int k = 0; k < 6; ++k) cpA[k] = cpB[k];

        __syncthreads();                         // means ready, B(p+1) landed
    }

    // ---------------- epilogue ----------------
    float b_[4];
#pragma unroll
    for (int j = 0; j < 4; ++j) b_[j] = bias[wc * 64 + j * 16 + rr];

    if (do_ln) {
        float g_[4], be_[4];
#pragma unroll
        for (int j = 0; j < 4; ++j) {
            int col = wc * 64 + j * 16 + rr;
            g_[j] = g[col]; be_[j] = be[col];
        }
        __syncthreads();                    // all waves done reading Bsm
        float* scr = (float*)Bsm;           // Bsm free now
#pragma unroll
        for (int pp = 0; pp < 4; ++pp) {
            int row = wr * 16 + qq * 4 + pp;
            float s1 = 0.f, s2 = 0.f;
#pragma unroll
            for (int j = 0; j < 4; ++j) {
                float v = gac[j][pp] + b_[j];
                gac[j][pp] = v;
                s1 += v; s2 += v * v;
            }
#pragma unroll
            for (int d = 1; d < 16; d <<= 1) {
                s1 += __shfl_xor(s1, d, 64);
                s2 += __shfl_xor(s2, d, 64);
            }
            if (rr == 0) {
                scr[row * 4 + wc * 2] = s1;
                scr[row * 4 + wc * 2 + 1] = s2;
            }
        }
        __syncthreads();
        unsigned short* O = (unsigned short*)outp;
#pragma unroll
        for (int pp = 0; pp < 4; ++pp) {
            int row = wr * 16 + qq * 4 + pp;
            float t1 = scr[row * 4] + scr[row * 4 + 2];
            float t2 = scr[row * 4 + 1] + scr[row * 4 + 3];
            float mu = t1 * (1.f / 128.f);
            float var = t2 * (1.f / 128.f) - mu * mu;
            float rs = rsqrtf(var + 1e-5f);
            if (m0 + row < N_NODES) {
#pragma unroll
                for (int j = 0; j < 4; ++j) {
                    float t = (gac[j][pp] - mu) * rs * g_[j] + be_[j];
                    t = t > 0.f ? t : 0.f;
                    O[(size_t)(m0 + row) * 128 + wc * 64 + j * 16 + rr] = f2bf(t);
                }
            }
        }
    } else {
        int is_bf = (int)flag[0];
#pragma unroll
        for (int pp = 0; pp < 4; ++pp) {
            int row = wr * 16 + qq * 4 + pp;
            if (m0 + row < N_NODES) {
                if (is_bf) {
                    unsigned short* O = (unsigned short*)outp;
#pragma unroll
                    for (int j = 0; j < 4; ++j)
                        O[(size_t)(m0 + row) * 128 + wc * 64 + j * 16 + rr] =
                            f2bf(gac[j][pp] + b_[j]);
                } else {
                    float* O = (float*)outp;
#pragma unroll
                    for (int j = 0; j < 4; ++j)
                        O[(size_t)(m0 + row) * 128 + wc * 64 + j * 16 + rr] =
                            gac[j][pp] + b_[j];
                }
            }
        }
    }
}

// ---------------- host ----------------

extern "C" void kernel_launch(void* const* d_in, const int* in_sizes, int n_in,
                              void* d_out, int out_size, void* d_ws, size_t ws_size,
                              hipStream_t stream) {
    const int* node_ids = (const int*)d_in[0];
    const int* ei = (const int*)d_in[1];
    const int* et = (const int*)d_in[2];
    const void* emb = d_in[3];
    const void* W1 = d_in[4];
    const void* r1 = d_in[5];
    const void* b1 = d_in[6];
    const void* g1 = d_in[7];
    const void* be1 = d_in[8];
    const void* W2 = d_in[9];
    const void* r2 = d_in[10];
    const void* b2 = d_in[11];
    const void* g2 = d_in[12];
    const void* be2 = d_in[13];
    const void* W3 = d_in[14];
    const void* r3 = d_in[15];
    const void* b3 = d_in[16];

    char* ws = (char*)d_ws;
    size_t off = 0;
    auto alloc = [&](size_t bytes) -> char* {
        char* p = ws + off;
        off = (off + bytes + 1023) & ~(size_t)1023;
        return p;
    };
    unsigned* cnt    = (unsigned*)alloc((size_t)NSEG * 4);            // zeroed
    size_t zero_end = off;
    unsigned* rank   = (unsigned*)alloc((size_t)N_EDGES * 4);
    unsigned* offs   = (unsigned*)alloc((size_t)(NSEG + 1) * 4);
    unsigned* escan  = (unsigned*)alloc((size_t)NSEG * 4);
    unsigned* bsum   = (unsigned*)alloc((size_t)SCAN_NB * 4);
    unsigned* boff   = (unsigned*)alloc((size_t)SCAN_NB * 4);
    unsigned* csr    = (unsigned*)alloc((size_t)N_EDGES * 4);
    unsigned short* WT = (unsigned short*)alloc((size_t)27 * 16384 * 2);
    float* vecs      = (float*)alloc((size_t)7 * 128 * 4);
    unsigned* flag   = (unsigned*)alloc(64);
    unsigned short* h0 = (unsigned short*)alloc((size_t)N_NODES * 128 * 2);
    unsigned short* h1 = (unsigned short*)alloc((size_t)N_NODES * 128 * 2);
    (void)ws_size; (void)in_sizes; (void)n_in; (void)out_size;

    k_detect<<<1, 64, 0, stream>>>((const unsigned*)g1, flag);
    k_zero<<<512, 256, 0, stream>>>((unsigned*)ws, (int)(zero_end / 4));
    k_count<<<(N_EDGES + 255) / 256, 256, 0, stream>>>(ei, et, cnt, rank);
    k_scan1<<<SCAN_NB, SCAN_B, 0, stream>>>(cnt, escan, bsum);
    k_scan2<<<1, 512, 0, stream>>>(bsum, boff, offs);
    k_scan3<<<SCAN_NB, SCAN_B, 0, stream>>>(escan, boff, offs);
    k_fill<<<(N_EDGES + 255) / 256, 256, 0, stream>>>(ei, et, offs, rank, csr);
    k_transw<<<(27 * 16384 + 255) / 256, 256, 0, stream>>>(flag, W1, r1, W2, r2, W3, r3, WT);
    k_cvtvec<<<7, 128, 0, stream>>>(flag, b1, g1, be1, b2, g2, be2, b3, vecs);
    k_gather<<<(N_NODES * 32 + 255) / 256, 256, 0, stream>>>(flag, node_ids, emb, h0);

    dim3 fgrid((N_NODES + MB - 1) / MB);   // 1563

    // layer 1: h0 -> h1
    k_fused<<<fgrid, 256, 0, stream>>>(h0, offs, csr, WT + (size_t)0 * 9 * 16384,
                                       vecs + 0 * 128, vecs + 1 * 128, vecs + 2 * 128,
                                       h1, 1, flag);
    // layer 2: h1 -> h0
    k_fused<<<fgrid, 256, 0, stream>>>(h1, offs, csr, WT + (size_t)1 * 9 * 16384,
                                       vecs + 3 * 128, vecs + 4 * 128, vecs + 5 * 128,
                                       h0, 1, flag);
    // layer 3: h0 -> out (no LN/ReLU; dtype by flag)
    k_fused<<<fgrid, 256, 0, stream>>>(h0, offs, csr, WT + (size_t)2 * 9 * 16384,
                                       vecs + 6 * 128, vecs + 1 * 128, vecs + 2 * 128,
                                       d_out, 0, flag);
}

// Round 9
// 499.995 us; speedup vs baseline: 1.3088x; 1.3088x over previous
//
#include <hip/hip_runtime.h>
#include <hip/hip_bf16.h>
#include <stdint.h>

// SememeRGCN on MI355X, v10: v9 geometry (32-node blocks, 40KB LDS -> 4
// blocks/CU) WITHOUT the launch-bounds occupancy pin.
// v9 lesson (rocprof): __launch_bounds__(256,4) made the allocator pick 64
// VGPRs + scratch-spill the 48-reg load burst (WRITE_SIZE 12.5->82.6MB,
// FETCH 83->196MB, 167us/layer) -- but 4 blocks/CU DID lift aggregate BW to
// 1.7TB/s. v10 drops the pin: LDS (40KB) alone caps at 4 blocks/CU, and the
// natural ~100-VGPR allocation (as in v5-v8, no spill) fits 4 waves/EU.
// Everything else as v9: pre-swizzled WT via global_load_lds, lane-parallel
// accumulate (8 lanes/node, 16ch/lane), csr/offs prefetch pipeline.

#define N_NODES 50000
#define N_EDGES 800000
#define R_REL 8
#define NSEG (N_NODES * R_REL)   // 400000 (rel, node) segments
#define MB 32                    // nodes per block

typedef __bf16 bf16_8 __attribute__((ext_vector_type(8)));
typedef float floatx4 __attribute__((ext_vector_type(4)));

static __device__ __forceinline__ float bf2f(unsigned short v) {
    unsigned u = ((unsigned)v) << 16;
    return __builtin_bit_cast(float, u);
}
static __device__ __forceinline__ unsigned short f2bf(float f) {
    unsigned u = __builtin_bit_cast(unsigned, f);
    u += 0x7FFFu + ((u >> 16) & 1u);   // round-to-nearest-even
    return (unsigned short)(u >> 16);
}
static __device__ __forceinline__ float bitf(unsigned u) {
    return __builtin_bit_cast(float, u);
}
// swizzled LDS byte offset: row-major 256B rows, XOR row bits into 16B slot
static __device__ __forceinline__ int sw(int row, int b) {
    return (row << 8) + (b ^ ((row & 7) << 4));
}
// async global->LDS, 16B per lane; lds dest wave-uniform base + lane*16
static __device__ __forceinline__ void gl_lds16(const unsigned short* g, char* l) {
    __builtin_amdgcn_global_load_lds(
        (const __attribute__((address_space(1))) unsigned int*)g,
        (__attribute__((address_space(3))) unsigned int*)l, 16, 0, 0);
}

// ---------------- dtype detection ----------------
__global__ void k_detect(const unsigned* __restrict__ g1, unsigned* __restrict__ flag) {
    if (threadIdx.x == 0 && blockIdx.x == 0)
        flag[0] = (g1[0] == 0x3F803F80u) ? 1u : 0u;
}

// ---------------- preprocessing ----------------

__global__ void k_zero(unsigned* __restrict__ p, int n_words) {
    int i = blockIdx.x * blockDim.x + threadIdx.x;
    int stride = gridDim.x * blockDim.x;
    for (; i < n_words; i += stride) p[i] = 0u;
}

// one atomic per edge; returned value IS the edge's rank within (rel,dst)
__global__ void k_count(const int* __restrict__ ei, const int* __restrict__ et,
                        unsigned* __restrict__ cnt, unsigned* __restrict__ rank) {
    int e = blockIdx.x * 256 + threadIdx.x;
    if (e >= N_EDGES) return;
    int dst = ei[N_EDGES + e];
    int t = et[e];
    rank[e] = atomicAdd(&cnt[t * N_NODES + dst], 1u);
}

// ---- 3-phase exclusive scan of cnt[400000] -> offs[400001] ----
#define SCAN_B 1024
#define SCAN_NB ((NSEG + SCAN_B - 1) / SCAN_B)   // 391

__global__ void k_scan1(const unsigned* __restrict__ deg, unsigned* __restrict__ escan,
                        unsigned* __restrict__ bsum) {
    __shared__ unsigned wsum[16];
    int tid = threadIdx.x;
    int lane = tid & 63, wid = tid >> 6;
    int i = blockIdx.x * SCAN_B + tid;
    unsigned v = (i < NSEG) ? deg[i] : 0u;
    unsigned incl = v;
#pragma unroll
    for (int d = 1; d < 64; d <<= 1) {
        unsigned t = __shfl_up(incl, d, 64);
        if (lane >= d) incl += t;
    }
    if (lane == 63) wsum[wid] = incl;
    __syncthreads();
    if (wid == 0 && lane < 16) {
        unsigned w = wsum[lane];
#pragma unroll
        for (int d = 1; d < 16; d <<= 1) {
            unsigned t = __shfl_up(w, d, 64);
            if (lane >= d) w += t;
        }
        wsum[lane] = w;
    }
    __syncthreads();
    unsigned woff = (wid == 0) ? 0u : wsum[wid - 1];
    if (i < NSEG) escan[i] = woff + incl - v;
    if (tid == 0) bsum[blockIdx.x] = wsum[15];
}

__global__ void k_scan2(const unsigned* __restrict__ bsum, unsigned* __restrict__ boff,
                        unsigned* __restrict__ offs) {
    __shared__ unsigned ws[8];
    int tid = threadIdx.x;
    int lane = tid & 63, w = tid >> 6;
    unsigned b = (tid < SCAN_NB) ? bsum[tid] : 0u;
    unsigned incl = b;
#pragma unroll
    for (int d = 1; d < 64; d <<= 1) {
        unsigned t = __shfl_up(incl, d, 64);
        if (lane >= d) incl += t;
    }
    if (lane == 63) ws[w] = incl;
    __syncthreads();
    unsigned wpre = 0;
    for (int i = 0; i < w; ++i) wpre += ws[i];
    if (tid < SCAN_NB) boff[tid] = wpre + incl - b;
    if (tid == 511) offs[NSEG] = wpre + incl;   // grand total = N_EDGES
}

__global__ void k_scan3(const unsigned* __restrict__ escan, const unsigned* __restrict__ boff,
                        unsigned* __restrict__ offs) {
    int i = blockIdx.x * SCAN_B + threadIdx.x;
    if (i < NSEG) offs[i] = escan[i] + boff[blockIdx.x];
}

// atomic-free fill: csr entry = src (dst implicit in segment), (rel,dst) sorted
__global__ void k_fill(const int* __restrict__ ei, const int* __restrict__ et,
                       const unsigned* __restrict__ offs, const unsigned* __restrict__ rank,
                       unsigned* __restrict__ csr) {
    int e = blockIdx.x * 256 + threadIdx.x;
    if (e >= N_EDGES) return;
    int src = ei[e];
    int dst = ei[N_EDGES + e];
    int t = et[e];
    csr[offs[(size_t)t * N_NODES + dst] + rank[e]] = (unsigned)src;
}

// transpose 27 [128x128] matrices to K-major bf16 with PRE-SWIZZLED rows:
// within each 256B output row o, 16B slot s holds original slot s^(o&7).
__global__ void k_transw(const unsigned* __restrict__ flag,
                         const void* __restrict__ W1, const void* __restrict__ r1,
                         const void* __restrict__ W2, const void* __restrict__ r2,
                         const void* __restrict__ W3, const void* __restrict__ r3,
                         unsigned short* __restrict__ WT) {
    int idx = blockIdx.x * 256 + threadIdx.x;
    if (idx >= 27 * 128 * 128) return;
    int is_bf = (int)flag[0];
    int m = idx >> 14;
    int r = idx & 16383;
    int o = r >> 7, d = r & 127;
    int l = m / 9, j = m % 9;
    const void* W = (l == 0) ? W1 : (l == 1) ? W2 : W3;
    const void* rt = (l == 0) ? r1 : (l == 1) ? r2 : r3;
    size_t eoff = (size_t)d * 128 + o;
    unsigned short v;
    if (j == 0) {
        v = is_bf ? ((const unsigned short*)rt)[eoff]
                  : f2bf(((const float*)rt)[eoff]);
    } else {
        size_t base = (size_t)(j - 1) * 16384;
        v = is_bf ? ((const unsigned short*)W)[base + eoff]
                  : f2bf(((const float*)W)[base + eoff]);
    }
    int selem = o * 128 + (((d >> 3) ^ (o & 7)) << 3) + (d & 7);
    WT[m * 16384 + selem] = v;
}

// gather emb[node_ids] -> x (bf16), 4 elems per thread
__global__ void k_gather(const unsigned* __restrict__ flag,
                         const int* __restrict__ ids, const void* __restrict__ emb,
                         unsigned short* __restrict__ x) {
    int c = blockIdx.x * 256 + threadIdx.x;
    if (c >= N_NODES * 32) return;
    int is_bf = (int)flag[0];
    int row = c >> 5, k = (c & 31) << 2;
    size_t s = (size_t)ids[row] * 128 + k;
    if (is_bf) {
        *(uint2*)&x[(size_t)row * 128 + k] = *(const uint2*)((const unsigned short*)emb + s);
    } else {
        const float4 f = *(const float4*)((const float*)emb + s);
        unsigned p0 = (unsigned)f2bf(f.x) | ((unsigned)f2bf(f.y) << 16);
        unsigned p1 = (unsigned)f2bf(f.z) | ((unsigned)f2bf(f.w) << 16);
        uint2 u; u.x = p0; u.y = p1;
        *(uint2*)&x[(size_t)row * 128 + k] = u;
    }
}

// convert 7 param vectors (b1,g1,be1,b2,g2,be2,b3) to fp32 canonical copies
__global__ void k_cvtvec(const unsigned* __restrict__ flag,
                         const void* p0, const void* p1, const void* p2,
                         const void* p3, const void* p4, const void* p5,
                         const void* p6, float* __restrict__ vecs) {
    int v = blockIdx.x, i = threadIdx.x;
    const void* p = (v == 0) ? p0 : (v == 1) ? p1 : (v == 2) ? p2 :
                    (v == 3) ? p3 : (v == 4) ? p4 : (v == 5) ? p5 : p6;
    float f = flag[0] ? bf2f(((const unsigned short*)p)[i]) : ((const float*)p)[i];
    vecs[v * 128 + i] = f;
}

// accumulate 8 channels (4 dwords = 8 bf16) into acc[base..base+7]
#define ACC8(v, base)                                                          \
    {                                                                          \
        acc[(base) + 0] += bitf((v).x << 16);                                  \
        acc[(base) + 1] += bitf((v).x & 0xFFFF0000u);                          \
        acc[(base) + 2] += bitf((v).y << 16);                                  \
        acc[(base) + 3] += bitf((v).y & 0xFFFF0000u);                          \
        acc[(base) + 4] += bitf((v).z << 16);                                  \
        acc[(base) + 5] += bitf((v).z & 0xFFFF0000u);                          \
        acc[(base) + 6] += bitf((v).w << 16);                                  \
        acc[(base) + 7] += bitf((v).w & 0xFFFF0000u);                          \
    }

// ---------------- fused RGCN layer ----------------
// block = 32 nodes, 256 threads (4 waves as 2x2: 16 rows x 64 cols each).
// out[n] = [x_n | mean_0(n) | ... | mean_7(n)] @ [root; W0..7] + bias
//          (then optional LN+ReLU), K = 9*128. 40KB LDS -> 4 blocks/CU.

__global__ __launch_bounds__(256) void k_fused(
    const unsigned short* __restrict__ X,     // [N,128] bf16 (layer input)
    const unsigned* __restrict__ offs,        // [NSEG+1], seg = rel*N + dst
    const unsigned* __restrict__ csr,         // [E] src ids
    const unsigned short* __restrict__ WTL,   // 9*[128][128] bf16, pre-swizzled
    const float* __restrict__ bias,
    const float* __restrict__ g,
    const float* __restrict__ be,
    void* __restrict__ outp,
    int do_ln,
    const unsigned* __restrict__ flag)
{
    __shared__ __align__(16) unsigned char lds[40960];
    char* Ab  = (char*)lds;            // 8KB A tile (32 rows x 128 k)
    char* Bsm = (char*)lds + 8192;     // 32KB B tile (128 out x 128 k)

    int tid = threadIdx.x;
    int m0 = blockIdx.x * MB;
    int lane = tid & 63, wv = tid >> 6;
    int rr = lane & 15, qq = lane >> 4;
    int wr = wv >> 1, wc = wv & 1;
    int gbw = m0 + wv * 8;             // this wave's first node (8 nodes/wave)
    int slot = lane >> 3;              // node slot (0..7)
    int cq = lane & 7;                 // 16B-pair index within row (0..7)

    // --- offs bounds: 9 lanes cover this wave's 8 nodes for rel 0 / rel 1 ---
    unsigned offA = 0, offB = 0;
    if (lane < 9) {
        int idx = gbw + lane; if (idx > N_NODES) idx = N_NODES;
        offA = offs[(size_t)0 * N_NODES + idx];
        offB = offs[(size_t)1 * N_NODES + idx];
    }

    floatx4 gac[4];
#pragma unroll
    for (int j = 0; j < 4; j++) gac[j] = (floatx4){0.f, 0.f, 0.f, 0.f};

    // prologue: issue B0 loads (async), stage x rows -> Ab (phase 0 = root)
#pragma unroll
    for (int i = 0; i < 8; ++i) {
        int cbase = i * 256 + wv * 64;           // wave-uniform chunk base
        gl_lds16(WTL + (size_t)(cbase + lane) * 8, Bsm + (size_t)cbase * 16);
    }
#pragma unroll
    for (int i = 0; i < 2; ++i) {
        int c = tid + i * 256;                   // 512 chunks of 16B
        int row = c >> 4, kg = c & 15;
        int grow = m0 + row; if (grow > N_NODES - 1) grow = N_NODES - 1;
        uint4 v = *(const uint4*)&X[(size_t)grow * 128 + kg * 8];
        *(uint4*)(Ab + sw(row, kg * 16)) = v;
    }

    // csr prefetch for rel 0 (6 entries per node-slot)
    unsigned cpA[6], cpB[6];
    {
        unsigned lo = __shfl(offA, slot, 64);
        unsigned hi = __shfl(offA, slot + 1, 64);
        unsigned cn = hi - lo;
#pragma unroll
        for (int k = 0; k < 6; ++k)
            if ((unsigned)k < cn) cpA[k] = csr[lo + k];
    }
    __syncthreads();                             // Ab + B0 landed

    for (int p = 0; p < 9; ++p) {
        // ---- MFMA phase p ----
#pragma unroll
        for (int kk = 0; kk < 4; ++kk) {
            int ko = kk * 64 + qq * 16;          // 16B chunk within 256B row
            bf16_8 a, b[4];
            a = *(const bf16_8*)(Ab + sw(wr * 16 + rr, ko));
#pragma unroll
            for (int j = 0; j < 4; ++j)
                b[j] = *(const bf16_8*)(Bsm + sw(wc * 64 + j * 16 + rr, ko));
#pragma unroll
            for (int j = 0; j < 4; ++j)
                gac[j] = __builtin_amdgcn_mfma_f32_16x16x32_bf16(a, b[j], gac[j], 0, 0, 0);
        }
        if (p == 8) break;
        __syncthreads();                         // all Ab/Bsm reads done

        // ---- stage B(p+1) async ----
        const unsigned short* WTn = WTL + (size_t)(p + 1) * 16384;
#pragma unroll
        for (int i = 0; i < 8; ++i) {
            int cbase = i * 256 + wv * 64;
            gl_lds16(WTn + (size_t)(cbase + lane) * 8, Bsm + (size_t)cbase * 16);
        }

        // ---- load burst: this wave's 8 nodes' edge rows (12 uint4 dests) ---
        unsigned lo0 = __shfl(offA, slot, 64);
        unsigned hi0 = __shfl(offA, slot + 1, 64);
        unsigned cnt0 = hi0 - lo0;
        uint4 ra[6], rb[6];
#pragma unroll
        for (int k = 0; k < 6; ++k) {
            if ((unsigned)k < cnt0) {
                const uint4* q = (const uint4*)(X + (size_t)cpA[k] * 128 + cq * 16);
                ra[k] = q[0]; rb[k] = q[1];
            }
        }

        // ---- prefetch csr entries for rel p+1 (overlaps row-load latency) --
        if (p + 1 < R_REL) {
            unsigned lo = __shfl(offB, slot, 64);
            unsigned hi = __shfl(offB, slot + 1, 64);
            unsigned cn = hi - lo;
#pragma unroll
            for (int k = 0; k < 6; ++k)
                if ((unsigned)k < cn) cpB[k] = csr[lo + k];
        }
        // ---- offs prefetch for rel p+2 ----
        unsigned offT = 0;
        if (p + 2 < R_REL && lane < 9) {
            int idx = gbw + lane; if (idx > N_NODES) idx = N_NODES;
            offT = offs[(size_t)(p + 2) * N_NODES + idx];
        }

        // ---- accumulate ----
        {
            float acc[16];
#pragma unroll
            for (int c = 0; c < 16; ++c) acc[c] = 0.f;
#pragma unroll
            for (int k = 0; k < 6; ++k)
                if ((unsigned)k < cnt0) { ACC8(ra[k], 0); ACC8(rb[k], 8); }
            unsigned i = 6;                      // rare tail (P(cnt>6)~0.5%)
            while (__any(i < cnt0)) {
                if (i < cnt0) {
                    unsigned e = csr[lo0 + i];
                    const uint4* q = (const uint4*)(X + (size_t)e * 128 + cq * 16);
                    uint4 ta = q[0], tb = q[1];
                    ACC8(ta, 0); ACC8(tb, 8);
                }
                ++i;
            }
            float inv = cnt0 ? 1.0f / (float)cnt0 : 0.0f;
            int nrow = wv * 8 + slot;
#pragma unroll
            for (int d = 0; d < 8; ++d) {
                unsigned w = (unsigned)f2bf(acc[2 * d] * inv) |
                             ((unsigned)f2bf(acc[2 * d + 1] * inv) << 16);
                *(unsigned*)(Ab + sw(nrow, cq * 32 + d * 4)) = w;
            }
        }

        // rotate prefetch registers
        offA = offB; offB = offT;
#pragma unroll
        for (int k = 0; k < 6; ++k) cpA[k] = cpB[k];

        __syncthreads();                         // means ready, B(p+1) landed
    }

    // ---------------- epilogue ----------------
    float b_[4];
#pragma unroll
    for (int j = 0; j < 4; ++j) b_[j] = bias[wc * 64 + j * 16 + rr];

    if (do_ln) {
        float g_[4], be_[4];
#pragma unroll
        for (int j = 0; j < 4; ++j) {
            int col = wc * 64 + j * 16 + rr;
            g_[j] = g[col]; be_[j] = be[col];
        }
        __syncthreads();                    // all waves done reading Bsm
        float* scr = (float*)Bsm;           // Bsm free now
#pragma unroll
        for (int pp = 0; pp < 4; ++pp) {
            int row = wr * 16 + qq * 4 + pp;
            float s1 = 0.f, s2 = 0.f;
#pragma unroll
            for (int j = 0; j < 4; ++j) {
                float v = gac[j][pp] + b_[j];
                gac[j][pp] = v;
                s1 += v; s2 += v * v;
            }
#pragma unroll
            for (int d = 1; d < 16; d <<= 1) {
                s1 += __shfl_xor(s1, d, 64);
                s2 += __shfl_xor(s2, d, 64);
            }
            if (rr == 0) {
                scr[row * 4 + wc * 2] = s1;
                scr[row * 4 + wc * 2 + 1] = s2;
            }
        }
        __syncthreads();
        unsigned short* O = (unsigned short*)outp;
#pragma unroll
        for (int pp = 0; pp < 4; ++pp) {
            int row = wr * 16 + qq * 4 + pp;
            float t1 = scr[row * 4] + scr[row * 4 + 2];
            float t2 = scr[row * 4 + 1] + scr[row * 4 + 3];
            float mu = t1 * (1.f / 128.f);
            float var = t2 * (1.f / 128.f) - mu * mu;
            float rs = rsqrtf(var + 1e-5f);
            if (m0 + row < N_NODES) {
#pragma unroll
                for (int j = 0; j < 4; ++j) {
                    float t = (gac[j][pp] - mu) * rs * g_[j] + be_[j];
                    t = t > 0.f ? t : 0.f;
                    O[(size_t)(m0 + row) * 128 + wc * 64 + j * 16 + rr] = f2bf(t);
                }
            }
        }
    } else {
        int is_bf = (int)flag[0];
#pragma unroll
        for (int pp = 0; pp < 4; ++pp) {
            int row = wr * 16 + qq * 4 + pp;
            if (m0 + row < N_NODES) {
                if (is_bf) {
                    unsigned short* O = (unsigned short*)outp;
#pragma unroll
                    for (int j = 0; j < 4; ++j)
                        O[(size_t)(m0 + row) * 128 + wc * 64 + j * 16 + rr] =
                            f2bf(gac[j][pp] + b_[j]);
                } else {
                    float* O = (float*)outp;
#pragma unroll
                    for (int j = 0; j < 4; ++j)
                        O[(size_t)(m0 + row) * 128 + wc * 64 + j * 16 + rr] =
                            gac[j][pp] + b_[j];
                }
            }
        }
    }
}

// ---------------- host ----------------

extern "C" void kernel_launch(void* const* d_in, const int* in_sizes, int n_in,
                              void* d_out, int out_size, void* d_ws, size_t ws_size,
                              hipStream_t stream) {
    const int* node_ids = (const int*)d_in[0];
    const int* ei = (const int*)d_in[1];
    const int* et = (const int*)d_in[2];
    const void* emb = d_in[3];
    const void* W1 = d_in[4];
    const void* r1 = d_in[5];
    const void* b1 = d_in[6];
    const void* g1 = d_in[7];
    const void* be1 = d_in[8];
    const void* W2 = d_in[9];
    const void* r2 = d_in[10];
    const void* b2 = d_in[11];
    const void* g2 = d_in[12];
    const void* be2 = d_in[13];
    const void* W3 = d_in[14];
    const void* r3 = d_in[15];
    const void* b3 = d_in[16];

    char* ws = (char*)d_ws;
    size_t off = 0;
    auto alloc = [&](size_t bytes) -> char* {
        char* p = ws + off;
        off = (off + bytes + 1023) & ~(size_t)1023;
        return p;
    };
    unsigned* cnt    = (unsigned*)alloc((size_t)NSEG * 4);            // zeroed
    size_t zero_end = off;
    unsigned* rank   = (unsigned*)alloc((size_t)N_EDGES * 4);
    unsigned* offs   = (unsigned*)alloc((size_t)(NSEG + 1) * 4);
    unsigned* escan  = (unsigned*)alloc((size_t)NSEG * 4);
    unsigned* bsum   = (unsigned*)alloc((size_t)SCAN_NB * 4);
    unsigned* boff   = (unsigned*)alloc((size_t)SCAN_NB * 4);
    unsigned* csr    = (unsigned*)alloc((size_t)N_EDGES * 4);
    unsigned short* WT = (unsigned short*)alloc((size_t)27 * 16384 * 2);
    float* vecs      = (float*)alloc((size_t)7 * 128 * 4);
    unsigned* flag   = (unsigned*)alloc(64);
    unsigned short* h0 = (unsigned short*)alloc((size_t)N_NODES * 128 * 2);
    unsigned short* h1 = (unsigned short*)alloc((size_t)N_NODES * 128 * 2);
    (void)ws_size; (void)in_sizes; (void)n_in; (void)out_size;

    k_detect<<<1, 64, 0, stream>>>((const unsigned*)g1, flag);
    k_zero<<<512, 256, 0, stream>>>((unsigned*)ws, (int)(zero_end / 4));
    k_count<<<(N_EDGES + 255) / 256, 256, 0, stream>>>(ei, et, cnt, rank);
    k_scan1<<<SCAN_NB, SCAN_B, 0, stream>>>(cnt, escan, bsum);
    k_scan2<<<1, 512, 0, stream>>>(bsum, boff, offs);
    k_scan3<<<SCAN_NB, SCAN_B, 0, stream>>>(escan, boff, offs);
    k_fill<<<(N_EDGES + 255) / 256, 256, 0, stream>>>(ei, et, offs, rank, csr);
    k_transw<<<(27 * 16384 + 255) / 256, 256, 0, stream>>>(flag, W1, r1, W2, r2, W3, r3, WT);
    k_cvtvec<<<7, 128, 0, stream>>>(flag, b1, g1, be1, b2, g2, be2, b3, vecs);
    k_gather<<<(N_NODES * 32 + 255) / 256, 256, 0, stream>>>(flag, node_ids, emb, h0);

    dim3 fgrid((N_NODES + MB - 1) / MB);   // 1563

    // layer 1: h0 -> h1
    k_fused<<<fgrid, 256, 0, stream>>>(h0, offs, csr, WT + (size_t)0 * 9 * 16384,
                                       vecs + 0 * 128, vecs + 1 * 128, vecs + 2 * 128,
                                       h1, 1, flag);
    // layer 2: h1 -> h0
    k_fused<<<fgrid, 256, 0, stream>>>(h1, offs, csr, WT + (size_t)1 * 9 * 16384,
                                       vecs + 3 * 128, vecs + 4 * 128, vecs + 5 * 128,
                                       h0, 1, flag);
    // layer 3: h0 -> out (no LN/ReLU; dtype by flag)
    k_fused<<<fgrid, 256, 0, stream>>>(h0, offs, csr, WT + (size_t)2 * 9 * 16384,
                                       vecs + 6 * 128, vecs + 1 * 128, vecs + 2 * 128,
                                       d_out, 0, flag);
}